// Round 11
// baseline (120.568 us; speedup 1.0000x reference)
//
#include <hip/hip_runtime.h>
#include <hip/hip_bf16.h>

#define N_NODES 100000
#define N_EDGES 1600000
#define HEADS 8
#define NH (N_NODES * HEADS)    // 800000
#define ALPHA 0.2f

#define BSHIFT 7
#define BSIZE 128               // dst nodes per bucket
#define NBUCK 782               // ceil(100000 / 128)
#define EPB 4096                // edges per hist/scatter block
#define NEB 391                 // ceil(1600000 / 4096)
#define GPROJ 782               // ceil(800000 / 1024) proj blocks (1024 thr)
#define CAP 3072                // per-chunk record capacity (mean 2046, +22 sigma)
#define RPT 6                   // CAP / 512 records per thread
#define NTILE 512               // norm: edges per block (2 per thread), 3125 blocks exact

typedef float floatx4 __attribute__((ext_vector_type(4)));

__device__ __forceinline__ float lrelu(float s) {
    return s >= 0.0f ? s : ALPHA * s;
}

// pr[dst] is a 64-byte record: floats [0..8) = p2 per head, [8..16) = 1/denom
// per head. One cache line serves BOTH dst-indexed gathers in norm.

// Kernel 1 (fused): blocks [0, GPROJ) compute per-node projections
// p1[n*8+h], pr[n*16+h]=p2; blocks [GPROJ, GPROJ+NEB) histogram dst buckets.
__global__ __launch_bounds__(1024) void proj_hist_kernel(
        const float* __restrict__ x, const float* __restrict__ a,
        const int* __restrict__ edge,
        float* __restrict__ p1, float* __restrict__ pr,
        unsigned* __restrict__ gcount) {
    __shared__ unsigned lh[NBUCK];
    int tid = threadIdx.x;
    if (blockIdx.x < GPROJ) {
        int t = blockIdx.x * 1024 + tid;
        if (t >= NH) return;
        int hd = t & 7;
        int n  = t >> 3;
        const float4* xp  = (const float4*)(x + (size_t)n * 128 + hd * 16);
        const float4* a1p = (const float4*)(a);
        const float4* a2p = (const float4*)(a + 16);
        float s1 = 0.f, s2 = 0.f;
#pragma unroll
        for (int i = 0; i < 4; ++i) {
            float4 xv = xp[i];
            float4 v1 = a1p[i];
            float4 v2 = a2p[i];
            s1 += xv.x * v1.x + xv.y * v1.y + xv.z * v1.z + xv.w * v1.w;
            s2 += xv.x * v2.x + xv.y * v2.y + xv.z * v2.z + xv.w * v2.w;
        }
        p1[t] = s1;
        pr[(size_t)n * 16 + hd] = s2;
    } else {
        for (int i = tid; i < NBUCK; i += 1024) lh[i] = 0;
        __syncthreads();
        int base = (blockIdx.x - GPROJ) * EPB;
#pragma unroll
        for (int k = 0; k < EPB / 1024; ++k) {
            int e = base + k * 1024 + tid;
            if (e < N_EDGES) atomicAdd(&lh[(unsigned)edge[N_EDGES + e] >> BSHIFT], 1u);
        }
        __syncthreads();
        for (int i = tid; i < NBUCK; i += 1024)
            if (lh[i]) atomicAdd(&gcount[i], lh[i]);
    }
}

// Kernel 2: exclusive scan of 782 bucket counts (single block).
__global__ __launch_bounds__(1024) void scan_kernel(const unsigned* __restrict__ gcount,
                                                    unsigned* __restrict__ goff,
                                                    unsigned* __restrict__ gcur) {
    __shared__ unsigned s[1024];
    int t = threadIdx.x;
    unsigned v = (t < NBUCK) ? gcount[t] : 0u;
    s[t] = v;
    __syncthreads();
    for (int d = 1; d < 1024; d <<= 1) {
        unsigned add = (t >= d) ? s[t - d] : 0u;
        __syncthreads();
        s[t] += add;
        __syncthreads();
    }
    if (t < NBUCK) {
        unsigned excl = s[t] - v;
        goff[t] = excl;
        gcur[t] = excl;
    }
    if (t == 0) goff[NBUCK] = N_EDGES;
}

// Kernel 3: scatter 4-byte records (src<<7 | dst_local) into bucket order.
__global__ __launch_bounds__(1024) void scatter_kernel(const int* __restrict__ edge,
                                                       unsigned* __restrict__ gcur,
                                                       unsigned* __restrict__ sorted) {
    __shared__ int lsrc[EPB];
    __shared__ int ldst[EPB];
    __shared__ unsigned lh[NBUCK];
    __shared__ unsigned lbase[NBUCK];
    int t = threadIdx.x;
    int base = blockIdx.x * EPB;
    for (int i = t; i < NBUCK; i += 1024) lh[i] = 0;
    __syncthreads();
#pragma unroll
    for (int k = 0; k < EPB / 1024; ++k) {
        int i = k * 1024 + t, e = base + i;
        if (e < N_EDGES) {
            lsrc[i] = edge[e];
            int d = edge[N_EDGES + e];
            ldst[i] = d;
            atomicAdd(&lh[(unsigned)d >> BSHIFT], 1u);
        }
    }
    __syncthreads();
    for (int i = t; i < NBUCK; i += 1024) {
        unsigned c = lh[i];
        lbase[i] = c ? atomicAdd(&gcur[i], c) : 0u;
        lh[i] = 0;   // reuse as local cursor
    }
    __syncthreads();
#pragma unroll
    for (int k = 0; k < EPB / 1024; ++k) {
        int i = k * 1024 + t, e = base + i;
        if (e < N_EDGES) {
            int d = ldst[i];
            unsigned b = (unsigned)d >> BSHIFT;
            unsigned pos = lbase[b] + atomicAdd(&lh[b], 1u);
            sorted[pos] = ((unsigned)lsrc[i] << BSHIFT) | (unsigned)(d & (BSIZE - 1));
        }
    }
}

// Kernel 4: one block per bucket, no float atomics. Counting-sort the bucket's
// records by dst_local in LDS; each thread owns (dl, head-pair) and serially
// accumulates its dst's edges in registers. Writes reciprocal denominators
// into the rd-half of pr[].
__global__ __launch_bounds__(512) void denom_kernel(const unsigned* __restrict__ sorted,
                                                    const unsigned* __restrict__ goff,
                                                    const float* __restrict__ p1,
                                                    float* __restrict__ pr) {
    __shared__ unsigned lsrc[CAP];     // 12 KB sorted-by-dl src indices
    __shared__ unsigned lh[BSIZE];     // per-dl count
    __shared__ unsigned lst[BSIZE];    // per-dl start
    __shared__ unsigned lcur[BSIZE];   // per-dl cursor
    __shared__ unsigned lscan[BSIZE];  // scan temp
    int t = threadIdx.x;
    int b = blockIdx.x;
    int dl = t >> 2;                   // 0..127: owned dst-local
    int hp = t & 3;                    // 0..3: owned head pair (2*hp, 2*hp+1)
    size_t node = (size_t)b * BSIZE + dl;
    bool valid = node < N_NODES;
    float p2a = 0.f, p2b = 0.f;
    if (valid) {
        float2 pv = *(const float2*)(pr + node * 16 + hp * 2);
        p2a = pv.x; p2b = pv.y;
    }
    float acc0 = 0.f, acc1 = 0.f;
    unsigned s0 = goff[b], s1 = goff[b + 1];

    for (unsigned cs = s0; cs < s1; cs += CAP) {
        unsigned cnt = min((unsigned)CAP, s1 - cs);
        if (t < BSIZE) lh[t] = 0;
        __syncthreads();
        unsigned recs[RPT];
#pragma unroll
        for (int k = 0; k < RPT; ++k) {
            unsigned i = (unsigned)t + (unsigned)k * 512u;
            bool v = i < cnt;
            recs[k] = v ? sorted[cs + i] : 0xFFFFFFFFu;
            if (v) atomicAdd(&lh[recs[k] & (BSIZE - 1)], 1u);
        }
        __syncthreads();
        if (t < BSIZE) lscan[t] = lh[t];
        __syncthreads();
        for (int d = 1; d < BSIZE; d <<= 1) {
            unsigned v = 0;
            if (t < BSIZE && t >= d) v = lscan[t - d];
            __syncthreads();
            if (t < BSIZE) lscan[t] += v;
            __syncthreads();
        }
        if (t < BSIZE) {
            unsigned st = lscan[t] - lh[t];
            lst[t] = st;
            lcur[t] = st;
        }
        __syncthreads();
#pragma unroll
        for (int k = 0; k < RPT; ++k) {
            unsigned r = recs[k];
            if (r != 0xFFFFFFFFu) {
                unsigned d = r & (BSIZE - 1);
                unsigned pos = atomicAdd(&lcur[d], 1u);
                lsrc[pos] = r >> BSHIFT;
            }
        }
        __syncthreads();
        unsigned e0 = lst[dl], e1 = lst[dl] + lh[dl];
        for (unsigned k = e0; k < e1; ++k) {
            unsigned src = lsrc[k];                       // broadcast to 4 lanes
            float2 pv = *(const float2*)(p1 + (size_t)src * 8 + hp * 2);
            acc0 += __expf(lrelu(pv.x + p2a));
            acc1 += __expf(lrelu(pv.y + p2b));
        }
        __syncthreads();   // protect lh/lst before next chunk
    }
    if (valid) {
        float2 o;
        o.x = 1.0f / (acc0 + 1e-16f);
        o.y = 1.0f / (acc1 + 1e-16f);
        *(float2*)(pr + node * 16 + 8 + hp * 2) = o;      // rd-half of pr
    }
}

// Kernel 5: edges in ORIGINAL order, TWO edges per thread from disjoint
// coalesced bands (B*512+t and B*512+256+t) -> 2x memory-level parallelism.
// Per edge: p1[src] (32B line) + pr[dst] (64B line, p2+rd together).
// Non-temporal edge loads (one-pass stream, don't evict gather tables) and
// non-temporal full-line output stores.
__global__ __launch_bounds__(256) void norm_kernel(const int* __restrict__ edge,
                                                   const float* __restrict__ p1,
                                                   const float* __restrict__ pr,
                                                   float* __restrict__ out) {
    int t = threadIdx.x;
    int base = blockIdx.x * NTILE;
    int e0 = base + t;
    int e1 = base + 256 + t;          // 3125*512 == N_EDGES exactly: no guards
    int src0 = __builtin_nontemporal_load(&edge[e0]);
    int src1 = __builtin_nontemporal_load(&edge[e1]);
    int dst0 = __builtin_nontemporal_load(&edge[N_EDGES + e0]);
    int dst1 = __builtin_nontemporal_load(&edge[N_EDGES + e1]);
    const float4* p1p0 = (const float4*)(p1 + (size_t)src0 * 8);
    const float4* prp0 = (const float4*)(pr + (size_t)dst0 * 16);
    const float4* p1p1 = (const float4*)(p1 + (size_t)src1 * 8);
    const float4* prp1 = (const float4*)(pr + (size_t)dst1 * 16);
    float4 s1a0 = p1p0[0], s1b0 = p1p0[1];
    float4 s1a1 = p1p1[0], s1b1 = p1p1[1];
    float4 s2a0 = prp0[0], s2b0 = prp0[1], ra0 = prp0[2], rb0 = prp0[3];
    float4 s2a1 = prp1[0], s2b1 = prp1[1], ra1 = prp1[2], rb1 = prp1[3];
    floatx4 o00, o01, o10, o11;
    o00.x = __expf(lrelu(s1a0.x + s2a0.x)) * ra0.x;
    o00.y = __expf(lrelu(s1a0.y + s2a0.y)) * ra0.y;
    o00.z = __expf(lrelu(s1a0.z + s2a0.z)) * ra0.z;
    o00.w = __expf(lrelu(s1a0.w + s2a0.w)) * ra0.w;
    o01.x = __expf(lrelu(s1b0.x + s2b0.x)) * rb0.x;
    o01.y = __expf(lrelu(s1b0.y + s2b0.y)) * rb0.y;
    o01.z = __expf(lrelu(s1b0.z + s2b0.z)) * rb0.z;
    o01.w = __expf(lrelu(s1b0.w + s2b0.w)) * rb0.w;
    o10.x = __expf(lrelu(s1a1.x + s2a1.x)) * ra1.x;
    o10.y = __expf(lrelu(s1a1.y + s2a1.y)) * ra1.y;
    o10.z = __expf(lrelu(s1a1.z + s2a1.z)) * ra1.z;
    o10.w = __expf(lrelu(s1a1.w + s2a1.w)) * ra1.w;
    o11.x = __expf(lrelu(s1b1.x + s2b1.x)) * rb1.x;
    o11.y = __expf(lrelu(s1b1.y + s2b1.y)) * rb1.y;
    o11.z = __expf(lrelu(s1b1.z + s2b1.z)) * rb1.z;
    o11.w = __expf(lrelu(s1b1.w + s2b1.w)) * rb1.w;
    floatx4* op0 = (floatx4*)(out + (size_t)e0 * 8);
    floatx4* op1 = (floatx4*)(out + (size_t)e1 * 8);
    __builtin_nontemporal_store(o00, op0);
    __builtin_nontemporal_store(o01, op0 + 1);
    __builtin_nontemporal_store(o10, op1);
    __builtin_nontemporal_store(o11, op1 + 1);
}

extern "C" void kernel_launch(void* const* d_in, const int* in_sizes, int n_in,
                              void* d_out, int out_size, void* d_ws, size_t ws_size,
                              hipStream_t stream) {
    const float* x    = (const float*)d_in[0];
    const float* a    = (const float*)d_in[1];
    const int*   edge = (const int*)d_in[2];
    float* out = (float*)d_out;

    // Workspace layout (~16.1 MB):
    unsigned* sorted = (unsigned*)d_ws;                              // 6.4 MB
    float*    p1     = (float*)(sorted + N_EDGES);                   // 3.2 MB
    float*    pr     = p1 + NH;                                      // 6.4 MB (p2+rd)
    unsigned* gcount = (unsigned*)(pr + (size_t)N_NODES * 16);       // 782
    unsigned* goff   = gcount + NBUCK;                               // 783
    unsigned* gcur   = goff + NBUCK + 1;                             // 782

    (void)hipMemsetAsync(gcount, 0, NBUCK * sizeof(unsigned), stream);

    proj_hist_kernel<<<GPROJ + NEB, 1024, 0, stream>>>(x, a, edge, p1, pr, gcount);
    scan_kernel<<<1, 1024, 0, stream>>>(gcount, goff, gcur);
    scatter_kernel<<<NEB, 1024, 0, stream>>>(edge, gcur, sorted);
    denom_kernel<<<NBUCK, 512, 0, stream>>>(sorted, goff, p1, pr);
    norm_kernel<<<N_EDGES / NTILE, 256, 0, stream>>>(edge, p1, pr, out);
}

// Round 13
// 96.881 us; speedup vs baseline: 1.2445x; 1.2445x over previous
//
#include <hip/hip_runtime.h>
#include <hip/hip_bf16.h>
#include <hip/hip_fp16.h>

#define N_NODES 100000
#define N_EDGES 1600000
#define HEADS 8
#define NH (N_NODES * HEADS)    // 800000
#define ALPHA 0.2f

#define BSHIFT 7
#define BSIZE 128               // dst nodes per bucket
#define NBUCK 782               // ceil(100000 / 128)
#define EPB 4096                // edges per hist/scatter block
#define NEB 391                 // ceil(1600000 / 4096)
#define GPROJ 782               // ceil(800000 / 1024) proj blocks (1024 thr)
#define CAP 3072                // per-chunk record capacity (mean 2046, +22 sigma)
#define RPT 6                   // CAP / 512 records per thread

typedef float floatx4 __attribute__((ext_vector_type(4)));

__device__ __forceinline__ float lrelu(float s) {
    return s >= 0.0f ? s : ALPHA * s;
}

// bf16 helpers (rd needs fp32 EXPONENT range: denom ~1e7 -> rd ~1e-7, which
// underflows fp16 subnormals -- the R12 failure -- but is a normal bf16).
__device__ __forceinline__ unsigned short f2bf(float f) {
    unsigned u = __float_as_uint(f);
    u += 0x7FFFu + ((u >> 16) & 1u);      // round-to-nearest-even
    return (unsigned short)(u >> 16);
}
__device__ __forceinline__ float bf2f(unsigned short s) {
    return __uint_as_float((unsigned)s << 16);
}

// Tables:
//   p1h[n*8+h]  : fp16 src-projection (range +-~16: fp16-safe)
//   prh[n*16+*] : 32-byte record = {fp16 p2[8] | bf16 rd[8]} -- one 32 B
//                 granule serves BOTH dst-indexed gathers in norm.
// denom accumulates from the SAME quantized p1/p2 that norm reads, so the
// softmax is self-consistent under quantization.

// Kernel 1 (fused): blocks [0, GPROJ) compute per-node projections;
// blocks [GPROJ, GPROJ+NEB) histogram dst buckets.
__global__ __launch_bounds__(1024) void proj_hist_kernel(
        const float* __restrict__ x, const float* __restrict__ a,
        const int* __restrict__ edge,
        __half* __restrict__ p1h, __half* __restrict__ prh,
        unsigned* __restrict__ gcount) {
    __shared__ unsigned lh[NBUCK];
    int tid = threadIdx.x;
    if (blockIdx.x < GPROJ) {
        int t = blockIdx.x * 1024 + tid;
        if (t >= NH) return;
        int hd = t & 7;
        int n  = t >> 3;
        const float4* xp  = (const float4*)(x + (size_t)n * 128 + hd * 16);
        const float4* a1p = (const float4*)(a);
        const float4* a2p = (const float4*)(a + 16);
        float s1 = 0.f, s2 = 0.f;
#pragma unroll
        for (int i = 0; i < 4; ++i) {
            float4 xv = xp[i];
            float4 v1 = a1p[i];
            float4 v2 = a2p[i];
            s1 += xv.x * v1.x + xv.y * v1.y + xv.z * v1.z + xv.w * v1.w;
            s2 += xv.x * v2.x + xv.y * v2.y + xv.z * v2.z + xv.w * v2.w;
        }
        p1h[t] = __float2half_rn(s1);
        prh[(size_t)n * 16 + hd] = __float2half_rn(s2);
    } else {
        for (int i = tid; i < NBUCK; i += 1024) lh[i] = 0;
        __syncthreads();
        int base = (blockIdx.x - GPROJ) * EPB;
#pragma unroll
        for (int k = 0; k < EPB / 1024; ++k) {
            int e = base + k * 1024 + tid;
            if (e < N_EDGES) atomicAdd(&lh[(unsigned)edge[N_EDGES + e] >> BSHIFT], 1u);
        }
        __syncthreads();
        for (int i = tid; i < NBUCK; i += 1024)
            if (lh[i]) atomicAdd(&gcount[i], lh[i]);
    }
}

// Kernel 2: exclusive scan of 782 bucket counts (single block).
__global__ __launch_bounds__(1024) void scan_kernel(const unsigned* __restrict__ gcount,
                                                    unsigned* __restrict__ goff,
                                                    unsigned* __restrict__ gcur) {
    __shared__ unsigned s[1024];
    int t = threadIdx.x;
    unsigned v = (t < NBUCK) ? gcount[t] : 0u;
    s[t] = v;
    __syncthreads();
    for (int d = 1; d < 1024; d <<= 1) {
        unsigned add = (t >= d) ? s[t - d] : 0u;
        __syncthreads();
        s[t] += add;
        __syncthreads();
    }
    if (t < NBUCK) {
        unsigned excl = s[t] - v;
        goff[t] = excl;
        gcur[t] = excl;
    }
    if (t == 0) goff[NBUCK] = N_EDGES;
}

// Kernel 3: scatter 4-byte records (src<<7 | dst_local) into bucket order.
__global__ __launch_bounds__(1024) void scatter_kernel(const int* __restrict__ edge,
                                                       unsigned* __restrict__ gcur,
                                                       unsigned* __restrict__ sorted) {
    __shared__ int lsrc[EPB];
    __shared__ int ldst[EPB];
    __shared__ unsigned lh[NBUCK];
    __shared__ unsigned lbase[NBUCK];
    int t = threadIdx.x;
    int base = blockIdx.x * EPB;
    for (int i = t; i < NBUCK; i += 1024) lh[i] = 0;
    __syncthreads();
#pragma unroll
    for (int k = 0; k < EPB / 1024; ++k) {
        int i = k * 1024 + t, e = base + i;
        if (e < N_EDGES) {
            lsrc[i] = edge[e];
            int d = edge[N_EDGES + e];
            ldst[i] = d;
            atomicAdd(&lh[(unsigned)d >> BSHIFT], 1u);
        }
    }
    __syncthreads();
    for (int i = t; i < NBUCK; i += 1024) {
        unsigned c = lh[i];
        lbase[i] = c ? atomicAdd(&gcur[i], c) : 0u;
        lh[i] = 0;   // reuse as local cursor
    }
    __syncthreads();
#pragma unroll
    for (int k = 0; k < EPB / 1024; ++k) {
        int i = k * 1024 + t, e = base + i;
        if (e < N_EDGES) {
            int d = ldst[i];
            unsigned b = (unsigned)d >> BSHIFT;
            unsigned pos = lbase[b] + atomicAdd(&lh[b], 1u);
            sorted[pos] = ((unsigned)lsrc[i] << BSHIFT) | (unsigned)(d & (BSIZE - 1));
        }
    }
}

// Kernel 4: one block per bucket, no float atomics. Counting-sort the bucket's
// records by dst_local in LDS; each thread owns (dl, head-pair) and serially
// accumulates its dst's edges in fp32 registers. Writes bf16 reciprocal
// denominators into the rd-half of prh.
__global__ __launch_bounds__(512) void denom_kernel(const unsigned* __restrict__ sorted,
                                                    const unsigned* __restrict__ goff,
                                                    const __half* __restrict__ p1h,
                                                    __half* __restrict__ prh) {
    __shared__ unsigned lsrc[CAP];     // 12 KB sorted-by-dl src indices
    __shared__ unsigned lh[BSIZE];     // per-dl count
    __shared__ unsigned lst[BSIZE];    // per-dl start
    __shared__ unsigned lcur[BSIZE];   // per-dl cursor
    __shared__ unsigned lscan[BSIZE];  // scan temp
    int t = threadIdx.x;
    int b = blockIdx.x;
    int dl = t >> 2;                   // 0..127: owned dst-local
    int hp = t & 3;                    // 0..3: owned head pair (2*hp, 2*hp+1)
    size_t node = (size_t)b * BSIZE + dl;
    bool valid = node < N_NODES;
    float p2a = 0.f, p2b = 0.f;
    if (valid) {
        float2 pv = __half22float2(*(const __half2*)(prh + node * 16 + hp * 2));
        p2a = pv.x; p2b = pv.y;
    }
    float acc0 = 0.f, acc1 = 0.f;
    unsigned s0 = goff[b], s1 = goff[b + 1];

    for (unsigned cs = s0; cs < s1; cs += CAP) {
        unsigned cnt = min((unsigned)CAP, s1 - cs);
        if (t < BSIZE) lh[t] = 0;
        __syncthreads();
        unsigned recs[RPT];
#pragma unroll
        for (int k = 0; k < RPT; ++k) {
            unsigned i = (unsigned)t + (unsigned)k * 512u;
            bool v = i < cnt;
            recs[k] = v ? sorted[cs + i] : 0xFFFFFFFFu;
            if (v) atomicAdd(&lh[recs[k] & (BSIZE - 1)], 1u);
        }
        __syncthreads();
        if (t < BSIZE) lscan[t] = lh[t];
        __syncthreads();
        for (int d = 1; d < BSIZE; d <<= 1) {
            unsigned v = 0;
            if (t < BSIZE && t >= d) v = lscan[t - d];
            __syncthreads();
            if (t < BSIZE) lscan[t] += v;
            __syncthreads();
        }
        if (t < BSIZE) {
            unsigned st = lscan[t] - lh[t];
            lst[t] = st;
            lcur[t] = st;
        }
        __syncthreads();
#pragma unroll
        for (int k = 0; k < RPT; ++k) {
            unsigned r = recs[k];
            if (r != 0xFFFFFFFFu) {
                unsigned d = r & (BSIZE - 1);
                unsigned pos = atomicAdd(&lcur[d], 1u);
                lsrc[pos] = r >> BSHIFT;
            }
        }
        __syncthreads();
        unsigned e0 = lst[dl], e1 = lst[dl] + lh[dl];
        for (unsigned k = e0; k < e1; ++k) {
            unsigned src = lsrc[k];                       // broadcast to 4 lanes
            float2 pv = __half22float2(*(const __half2*)(p1h + (size_t)src * 8 + hp * 2));
            acc0 += __expf(lrelu(pv.x + p2a));
            acc1 += __expf(lrelu(pv.y + p2b));
        }
        __syncthreads();   // protect lh/lst before next chunk
    }
    if (valid) {
        unsigned short r0 = f2bf(1.0f / (acc0 + 1e-16f));
        unsigned short r1 = f2bf(1.0f / (acc1 + 1e-16f));
        // rd-half of prh (4-byte aligned: byte offset node*32 + 16 + hp*4)
        *(unsigned*)((unsigned short*)prh + node * 16 + 8 + hp * 2) =
            ((unsigned)r1 << 16) | r0;
    }
}

// Kernel 5: edges in ORIGINAL order -> coalesced edge reads and out writes.
// Per edge: p1h[src] (16 B fp16) + prh[dst] (32 B, fp16 p2 + bf16 rd).
// Non-temporal full-line out stores.
__global__ __launch_bounds__(256) void norm_kernel(const int* __restrict__ edge,
                                                   const __half* __restrict__ p1h,
                                                   const __half* __restrict__ prh,
                                                   float* __restrict__ out) {
    int e = blockIdx.x * 256 + threadIdx.x;
    if (e >= N_EDGES) return;
    int src = edge[e];
    int dst = edge[N_EDGES + e];
    float4 pv = *(const float4*)(p1h + (size_t)src * 8);       // 8 fp16 p1
    float4 qa = *(const float4*)(prh + (size_t)dst * 16);      // 8 fp16 p2
    float4 qb = *(const float4*)(prh + (size_t)dst * 16 + 8);  // 8 bf16 rd
    const __half2* s1p = (const __half2*)&pv;
    const __half2* s2p = (const __half2*)&qa;
    const unsigned short* rdu = (const unsigned short*)&qb;
    floatx4 o0, o1;
    float ov[8];
#pragma unroll
    for (int k = 0; k < 4; ++k) {
        float2 f1 = __half22float2(s1p[k]);
        float2 f2 = __half22float2(s2p[k]);
        ov[2 * k]     = __expf(lrelu(f1.x + f2.x)) * bf2f(rdu[2 * k]);
        ov[2 * k + 1] = __expf(lrelu(f1.y + f2.y)) * bf2f(rdu[2 * k + 1]);
    }
    o0.x = ov[0]; o0.y = ov[1]; o0.z = ov[2]; o0.w = ov[3];
    o1.x = ov[4]; o1.y = ov[5]; o1.z = ov[6]; o1.w = ov[7];
    floatx4* op = (floatx4*)(out + (size_t)e * 8);
    __builtin_nontemporal_store(o0, op);
    __builtin_nontemporal_store(o1, op + 1);
}

extern "C" void kernel_launch(void* const* d_in, const int* in_sizes, int n_in,
                              void* d_out, int out_size, void* d_ws, size_t ws_size,
                              hipStream_t stream) {
    const float* x    = (const float*)d_in[0];
    const float* a    = (const float*)d_in[1];
    const int*   edge = (const int*)d_in[2];
    float* out = (float*)d_out;

    // Workspace layout (~11.2 MB):
    unsigned* sorted = (unsigned*)d_ws;                              // 6.4 MB
    __half*   p1h    = (__half*)(sorted + N_EDGES);                  // 1.6 MB
    __half*   prh    = p1h + NH;                                     // 3.2 MB (p2+rd)
    unsigned* gcount = (unsigned*)(prh + (size_t)N_NODES * 16);      // 782
    unsigned* goff   = gcount + NBUCK;                               // 783
    unsigned* gcur   = goff + NBUCK + 1;                             // 782

    (void)hipMemsetAsync(gcount, 0, NBUCK * sizeof(unsigned), stream);

    proj_hist_kernel<<<GPROJ + NEB, 1024, 0, stream>>>(x, a, edge, p1h, prh, gcount);
    scan_kernel<<<1, 1024, 0, stream>>>(gcount, goff, gcur);
    scatter_kernel<<<NEB, 1024, 0, stream>>>(edge, gcur, sorted);
    denom_kernel<<<NBUCK, 512, 0, stream>>>(sorted, goff, p1h, prh);
    norm_kernel<<<(N_EDGES + 255) / 256, 256, 0, stream>>>(edge, p1h, prh, out);
}